// Round 4
// baseline (705.839 us; speedup 1.0000x reference)
//
#include <hip/hip_runtime.h>
#include <cstdint>
#include <cstddef>

#define D_MODEL 1024
#define SEQ     4096
#define BATCH   4
#define M_ROWS  (BATCH*SEQ)   // 16384
#define NCHUNK  64
#define LCHUNK  (SEQ/NCHUNK)  // 64

typedef __bf16 bf16_t;
typedef __bf16 bf16x8 __attribute__((ext_vector_type(8)));
typedef __bf16 bf16x4 __attribute__((ext_vector_type(4)));
typedef float  f32x4  __attribute__((ext_vector_type(4)));

// ---------------------------------------------------------------- utilities
__device__ __forceinline__ void load_lds_128(const bf16_t* g, bf16_t* l) {
    __builtin_amdgcn_global_load_lds(
        (const __attribute__((address_space(1))) unsigned int*)g,
        (__attribute__((address_space(3))) unsigned int*)l,
        16, 0, 0);
}

__device__ __forceinline__ float2 bf16pair_to_f2(unsigned int u) {
    union { unsigned int i; float f; } a, b;
    a.i = u << 16;          // low element
    b.i = u & 0xffff0000u;  // high element
    float2 r; r.x = a.f; r.y = b.f; return r;
}

// tanh-form GELU: max |err| vs exact erf-GELU ~5e-4, below bf16 quantization
// of the activation tensor; one v_exp instead of erff's ~20-op polynomial.
__device__ __forceinline__ float gelu_f(float x) {
    float t = x * x;
    float u = x * (1.5957691216f + 0.07135481627f * t);   // 2c(x+0.044715x^3)
    return x / (1.0f + __expf(-u));
}

// ---------------------------------------------- fused weight convert+transpose
// all four weights in one launch; in: f32 (R,C) row-major -> out: bf16 (C,R)
__global__ __launch_bounds__(256)
void transpose_all(const float* __restrict__ gate_w, const float* __restrict__ value_w,
                   const float* __restrict__ ffn_w1, const float* __restrict__ ffn_w2,
                   bf16_t* __restrict__ wgv_t, bf16_t* __restrict__ w1_t,
                   bf16_t* __restrict__ w2_t) {
    int id = blockIdx.x;
    const float* in; bf16_t* outp; int R, C, bx, by;
    if (id < 1024)      { in = gate_w;  outp = wgv_t;               R = 1024; C = 1024; bx = id & 31;  by = id >> 5; }
    else if (id < 2048) { id -= 1024; in = value_w; outp = wgv_t + 1024*1024; R = 1024; C = 1024; bx = id & 31;  by = id >> 5; }
    else if (id < 6144) { id -= 2048; in = ffn_w1;  outp = w1_t;    R = 1024; C = 4096; bx = id & 127; by = id >> 7; }
    else                { id -= 6144; in = ffn_w2;  outp = w2_t;    R = 4096; C = 1024; bx = id & 31;  by = id >> 5; }
    __shared__ float t[32][33];
    int tx = threadIdx.x & 31, ty = threadIdx.x >> 5;   // 32 x 8
    int c0 = bx * 32, r0 = by * 32;
    #pragma unroll
    for (int j = 0; j < 32; j += 8)
        t[ty + j][tx] = in[(size_t)(r0 + ty + j) * C + c0 + tx];
    __syncthreads();
    #pragma unroll
    for (int j = 0; j < 32; j += 8)
        outp[(size_t)(c0 + ty + j) * R + r0 + tx] = (bf16_t)t[tx][ty + j];
}

// ---------------------------------------------------------------- layernorm
__global__ __launch_bounds__(256)
void ln_kernel(const float* __restrict__ x, const float* __restrict__ gamma,
               const float* __restrict__ beta, bf16_t* __restrict__ h) {
    int row = blockIdx.x;
    int tid = threadIdx.x;
    const float4* xr = (const float4*)(x + (size_t)row * D_MODEL);
    float4 v = xr[tid];
    float s  = v.x + v.y + v.z + v.w;
    float ss = v.x*v.x + v.y*v.y + v.z*v.z + v.w*v.w;
    #pragma unroll
    for (int off = 32; off; off >>= 1) {
        s  += __shfl_down(s, off);
        ss += __shfl_down(ss, off);
    }
    __shared__ float red[8];
    int wave = tid >> 6, lane = tid & 63;
    if (lane == 0) { red[wave] = s; red[4 + wave] = ss; }
    __syncthreads();
    if (tid == 0) {
        float S  = red[0] + red[1] + red[2] + red[3];
        float SS = red[4] + red[5] + red[6] + red[7];
        float mean = S * (1.0f / D_MODEL);
        float var  = SS * (1.0f / D_MODEL) - mean * mean;
        red[0] = mean;
        red[1] = rsqrtf(var + 1e-5f);
    }
    __syncthreads();
    float mean = red[0], rstd = red[1];
    float4 gv = ((const float4*)gamma)[tid];
    float4 bv = ((const float4*)beta)[tid];
    bf16x4 o;
    o[0] = (bf16_t)((v.x - mean) * rstd * gv.x + bv.x);
    o[1] = (bf16_t)((v.y - mean) * rstd * gv.y + bv.y);
    o[2] = (bf16_t)((v.z - mean) * rstd * gv.z + bv.z);
    o[3] = (bf16_t)((v.w - mean) * rstd * gv.w + bv.w);
    ((bf16x4*)h)[(size_t)row * (D_MODEL / 4) + tid] = o;
}

// ----------------- GEMM 256x256, 4 super-phases, persistent, A-ring-of-3
// A: bf16 (M,K) row-major.  Bt: bf16 (N,K) row-major.
// Persistent stream-K (r2): grid=256, one 256-row m-band x TPB n-tiles per
// block, one continuous K-tile stream. r4 change: DEEPEN THE PREFETCH RING.
// Evidence: r1/r2/r3 + r0's 4-block/CU structure ALL plateau at ~36% MfmaUtil
// regardless of barrier density -> the stall is vmcnt-wait tail latency:
// r3's binding waits protect loads issued only 1 super-phase earlier, so the
// loop equilibrates at (load tail latency - 1 phase) of stall per phase.
// m201's verified 62% keeps 3 half-tiles in flight. Fix: use the idle 32 KiB
// of LDS (160 total) for a THIRD A buffer. Rings: A = {a0,a1,a2} (tile%3),
// B = {b0,b1} (tile parity). Stage slots (4 loads/thread each):
//   SP1: rd a0.m0-3 + b0.all | stage A(s2)->a2            | mfma s0 m0-3
//   SP2: rd a0.m4-7          | stage B(s2)->b0 | vmcnt(8) | mfma s0 m4-7
//   SP3: rd a1.m0-3 + b1.all | stage A(s3)->a0            | mfma s1 m0-3
//   SP4: rd a1.m4-7          | stage B(s3)->b1 | vmcnt(8) | mfma s1 m4-7
//   rotate (a0,a1,a2) <- (a2,a0,a1)
// Ledger: 16 loads in flight; SP2's vmcnt(8) drains A(s1),B(s1) (issued 3 and
// 2 SPs earlier, needed at SP3); SP4's drains A(s2),B(s2) (3 and 2 SPs, needed
// next SP1). Issue-to-drain slack doubles vs r3 (was 1 SP binding).
// Region audit (overwrite-after-read): A(s2)->a2 occupant A(2it-1) last read
// SP4(it-1); A(s3)->a0 occupant A(s0) last read SP2; B(s2)->b0 occupant B(s0)
// last read SP1; B(s3)->b1 occupant B(s1) last read SP3 -- every DMA issues
// >=1 END-barrier after its region's last ds_read. Tail: last iteration is
// PEELED (no stages, vmcnt(0) at its SP2) -- no junk loads, exact ledger.
// MODE 2: out_bf16 = gelu_tanh(acc + bias)
// MODE 3: out_f32  = xres + acc + bias
// MODE 4: fused gate/value: n<1024 -> sigmoid(acc+bias) -> out; else acc+bias2 -> out2
#define FENCE() asm volatile("" ::: "memory")
#define SP_MID() do { FENCE(); __builtin_amdgcn_s_barrier(); FENCE(); \
    __builtin_amdgcn_s_setprio(1); } while (0)
#define SP_END() do { __builtin_amdgcn_s_setprio(0); FENCE(); \
    __builtin_amdgcn_s_barrier(); FENCE(); } while (0)
#define VMW8() asm volatile("s_waitcnt vmcnt(8)" ::: "memory")
#define VMW0() asm volatile("s_waitcnt vmcnt(0)" ::: "memory")

#define LDA4(BUF, MB) do { _Pragma("unroll") for (int m_ = 0; m_ < 4; ++m_) { \
    af[m_][0] = *(const bf16x8*)((BUF) + aoff0 + ((MB)*4 + m_) * 1024); \
    af[m_][1] = *(const bf16x8*)((BUF) + aoff1 + ((MB)*4 + m_) * 1024); } } while (0)
#define LDB4(BUF) do { _Pragma("unroll") for (int n_ = 0; n_ < 4; ++n_) { \
    bfr[n_][0] = *(const bf16x8*)((BUF) + boff0 + n_ * 1024); \
    bfr[n_][1] = *(const bf16x8*)((BUF) + boff1 + n_ * 1024); } } while (0)
#define MFMA_HALF(MB, NLO) do { _Pragma("unroll") for (int m_ = 0; m_ < 4; ++m_) { \
    _Pragma("unroll") for (int n_ = 0; n_ < 2; ++n_) { \
        acc[(MB)*4 + m_][(NLO) + n_] = __builtin_amdgcn_mfma_f32_16x16x32_bf16( \
            bfr[(NLO)+n_][0], af[m_][0], acc[(MB)*4 + m_][(NLO) + n_], 0, 0, 0); \
        acc[(MB)*4 + m_][(NLO) + n_] = __builtin_amdgcn_mfma_f32_16x16x32_bf16( \
            bfr[(NLO)+n_][1], af[m_][1], acc[(MB)*4 + m_][(NLO) + n_], 0, 0, 0); } } } while (0)

template <int MODE, int TN, int TPB, int LKT>
__global__ __launch_bounds__(512, 2)
void gemm256(const bf16_t* __restrict__ A, const bf16_t* __restrict__ Bt,
             const float* __restrict__ bias, const float* __restrict__ bias2,
             const float* __restrict__ xres,
             void* __restrict__ out, void* __restrict__ out2,
             int M, int N, int K) {
    __shared__ __align__(16) bf16_t ldsA[3][256 * 64];   // 96 KiB, ring of 3
    __shared__ __align__(16) bf16_t ldsB[2][256 * 64];   // 64 KiB, ring of 2

    const int KT = 1 << LKT;       // K-tiles per output tile (K/64)
    const int S  = TPB * KT;       // stream length
    const int NI = S >> 1;         // iterations (2 K-tiles each)

    const int tid  = threadIdx.x;
    const int lane = tid & 63;
    const int wave = tid >> 6;
    const int wm   = wave >> 2;      // 0..1  (m half)
    const int wn   = wave & 3;       // 0..3  (n quarter)

    const int L    = blockIdx.x;
    const int i    = L >> 3;
    const int ngrp = i & 3;                       // TN/TPB == 4 for all shapes
    const int mb   = (L & 7) + 8 * (i >> 2);      // XCD-local m-band
    const int m0   = mb * 256;
    const int n00  = ngrp * TPB * 256;            // first owned n-tile

    f32x4 acc[8][4];
    #pragma unroll
    for (int ii = 0; ii < 8; ii++)
        #pragma unroll
        for (int j = 0; j < 4; j++) acc[ii][j] = (f32x4){0.f, 0.f, 0.f, 0.f};

    // staging invariants: row = tid>>3 (0..63 per half-load), source col8
    // pre-swizzled by row&7 so linear LDS holds the XOR layout.
    const int rr = tid >> 3;                        // 0..63
    const int sc = ((tid & 7) ^ (rr & 7)) * 8;      // swizzled col (bf16 units)
    const bf16_t* pa0 = A  + ((size_t)(m0  + rr)) * K + sc;
    const bf16_t* pb0 = Bt + ((size_t)(n00 + rr)) * K + sc;
    const size_t rstep   = (size_t)64 * K;          // rows 64..127 of a half
    const size_t hstep   = rstep * 2;               // half-tile stride (128 rows)
    const size_t nstride = (size_t)256 * K;         // next n-tile of B

    // stream-tile address helpers (A is periodic in KT: same m-band every tile)
    #define PA(s) (pa0 + (((s) & (KT - 1)) << 6))
    #define PB(s) (pb0 + (size_t)((s) >> LKT) * nstride + (((s) & (KT - 1)) << 6))

    // frag-read invariants
    const int l16 = lane & 15, quad = lane >> 4, swz = l16 & 7;
    const int aoff0 = (wm*128 + l16)*64 + ((quad    ) ^ swz)*8;
    const int aoff1 = (wm*128 + l16)*64 + ((quad + 4) ^ swz)*8;
    const int boff0 = (wn*64  + l16)*64 + ((quad    ) ^ swz)*8;
    const int boff1 = (wn*64  + l16)*64 + ((quad + 4) ^ swz)*8;

    bf16_t* a0 = &ldsA[0][0];
    bf16_t* a1 = &ldsA[1][0];
    bf16_t* a2 = &ldsA[2][0];
    bf16_t* b0 = &ldsB[0][0];
    bf16_t* b1 = &ldsB[1][0];

    // full-tile stage: 256 rows = 4 global_load_lds per thread
    auto STAGE_T = [&](const bf16_t* gsrc, bf16_t* dst) {
        load_lds_128(gsrc,                 dst + tid * 8);
        load_lds_128(gsrc + rstep,         dst + 4096  + tid * 8);
        load_lds_128(gsrc + hstep,         dst + 8192  + tid * 8);
        load_lds_128(gsrc + hstep + rstep, dst + 12288 + tid * 8);
    };

    // epilogue for output tile 'tdone' (acc -> MODE-specific store), resets acc
    auto EPILOGUE = [&](int tdone) {
        const int nn0 = n00 + tdone * 256;
        #pragma unroll
        for (int mt = 0; mt < 8; ++mt) {
            int row = m0 + wm * 128 + mt * 16 + l16;
            #pragma unroll
            for (int nt = 0; nt < 4; ++nt) {
                int col = nn0 + wn * 64 + nt * 16 + quad * 4;
                f32x4 a = acc[mt][nt];
                if (MODE == 4) {
                    bool isV = (nn0 >= 1024);         // tile-uniform
                    int c1 = col & 1023;
                    float4 bv = *(const float4*)((isV ? bias2 : bias) + c1);
                    float4 val;
                    val.x = a[0] + bv.x; val.y = a[1] + bv.y;
                    val.z = a[2] + bv.z; val.w = a[3] + bv.w;
                    if (!isV) {
                        val.x = 1.0f / (1.0f + __expf(-val.x));
                        val.y = 1.0f / (1.0f + __expf(-val.y));
                        val.z = 1.0f / (1.0f + __expf(-val.z));
                        val.w = 1.0f / (1.0f + __expf(-val.w));
                    }
                    bf16x4 p;
                    p[0] = (bf16_t)val.x; p[1] = (bf16_t)val.y;
                    p[2] = (bf16_t)val.z; p[3] = (bf16_t)val.w;
                    bf16_t* o = (bf16_t*)(isV ? out2 : out);
                    *(bf16x4*)(o + (size_t)row * 1024 + c1) = p;
                } else if (MODE == 2) {
                    float4 bv = *(const float4*)(bias + col);
                    bf16x4 p;
                    p[0] = (bf16_t)gelu_f(a[0] + bv.x);
                    p[1] = (bf16_t)gelu_f(a[1] + bv.y);
                    p[2] = (bf16_t)gelu_f(a[2] + bv.z);
                    p[3] = (bf16_t)gelu_f(a[3] + bv.w);
                    *(bf16x4*)((bf16_t*)out + (size_t)row * N + col) = p;
                } else { // MODE 3
                    float4 bv = *(const float4*)(bias + col);
                    float4 xr = *(const float4*)(xres + (size_t)row * N + col);
                    float4 val;
                    val.x = xr.x + a[0] + bv.x; val.y = xr.y + a[1] + bv.y;
                    val.z = xr.z + a[2] + bv.z; val.w = xr.w + a[3] + bv.w;
                    *(float4*)((float*)out + (size_t)row * N + col) = val;
                }
                acc[mt][nt] = (f32x4){0.f, 0.f, 0.f, 0.f};
            }
        }
    };

    // prologue: A(0)->a0, B(0)->b0, A(1)->a1, B(1)->b1 (16 loads), full drain
    STAGE_T(PA(0), a0);
    STAGE_T(PB(0), b0);
    STAGE_T(PA(1), a1);
    STAGE_T(PB(1), b1);
    VMW0();
    __builtin_amdgcn_s_barrier();
    FENCE();

    bf16x8 af[4][2], bfr[4][2];

    #pragma unroll 1
    for (int it = 0; it < NI - 1; ++it) {
        const int s2 = 2*it + 2;
        const int s3 = 2*it + 3;

        // SP1: tile s0 m0-3 | stage A(s2)->a2 (3-SP slack)
        STAGE_T(PA(s2), a2);
        LDA4(a0, 0); LDB4(b0);
        SP_MID(); MFMA_HALF(0, 0); MFMA_HALF(0, 2); SP_END();
        // SP2: tile s0 m4-7 | stage B(s2)->b0 | drain A(s1),B(s1) for SP3
        STAGE_T(PB(s2), b0);
        LDA4(a0, 1);
        VMW8();
        SP_MID(); MFMA_HALF(1, 0); MFMA_HALF(1, 2); SP_END();
        // SP3: tile s1 m0-3 | stage A(s3)->a0 (3-SP slack)
        STAGE_T(PA(s3), a0);
        LDA4(a1, 0); LDB4(b1);
        SP_MID(); MFMA_HALF(0, 0); MFMA_HALF(0, 2); SP_END();
        // SP4: tile s1 m4-7 | stage B(s3)->b1 | drain A(s2),B(s2) for next SP1
        STAGE_T(PB(s3), b1);
        LDA4(a1, 1);
        VMW8();
        SP_MID(); MFMA_HALF(1, 0); MFMA_HALF(1, 2); SP_END();

        // rotate A ring: next s0 lives in a2 (just staged), next s1 in a0
        bf16_t* t = a0; a0 = a2; a2 = a1; a1 = t;

        // output-tile boundary (never the final tile; that's after the peel)
        if (((it + 1) & ((KT >> 1) - 1)) == 0)
            EPILOGUE((2*it + 1) >> LKT);
    }

    // ---- peeled final iteration: no staging, exact drain
    LDA4(a0, 0); LDB4(b0);
    SP_MID(); MFMA_HALF(0, 0); MFMA_HALF(0, 2); SP_END();
    LDA4(a0, 1);
    VMW0();                       // drains A(S-1),B(S-1) staged last iteration
    SP_MID(); MFMA_HALF(1, 0); MFMA_HALF(1, 2); SP_END();
    LDA4(a1, 0); LDB4(b1);
    SP_MID(); MFMA_HALF(0, 0); MFMA_HALF(0, 2); SP_END();
    LDA4(a1, 1);
    SP_MID(); MFMA_HALF(1, 0); MFMA_HALF(1, 2); SP_END();

    EPILOGUE(TPB - 1);
    #undef PA
    #undef PB
}

// ---------------------------------------------------------------- scan
// phase A: per-chunk sums of g and g*v
__global__ __launch_bounds__(256)
void scan_partial(const bf16_t* __restrict__ g, const bf16_t* __restrict__ v,
                  float* __restrict__ sg, float* __restrict__ sgv) {
    int dt = blockIdx.x & 1;
    int c  = (blockIdx.x >> 1) & (NCHUNK - 1);
    int b  = blockIdx.x >> 7;
    int d  = dt * 512 + threadIdx.x * 2;
    float s0 = 0.f, s1 = 0.f, t0 = 0.f, t1 = 0.f;
    for (int i = 0; i < LCHUNK; i++) {
        int s = c * LCHUNK + i;
        size_t idx = ((size_t)(b * SEQ + s)) * D_MODEL + d;
        float2 gf = bf16pair_to_f2(*(const unsigned int*)(g + idx));
        float2 vf = bf16pair_to_f2(*(const unsigned int*)(v + idx));
        s0 += gf.x; s1 += gf.y;
        t0 += gf.x * vf.x; t1 += gf.y * vf.y;
    }
    size_t o = ((size_t)(b * NCHUNK + c)) * D_MODEL + d;
    sg[o] = s0;  sg[o + 1] = s1;
    sgv[o] = t0; sgv[o + 1] = t1;
}

// phase B+C fused: each block sums partials of chunks < c (2 MB, L2-resident),
// then applies x_new = x + cumsum(g*v)/(cumsum(g)+eps)
__global__ __launch_bounds__(256)
void scan_apply(const bf16_t* __restrict__ g, const bf16_t* __restrict__ v,
                const float* __restrict__ x, const float* __restrict__ sg,
                const float* __restrict__ sgv, float* __restrict__ out) {
    int dt = blockIdx.x & 1;
    int c  = (blockIdx.x >> 1) & (NCHUNK - 1);
    int b  = blockIdx.x >> 7;
    int d  = dt * 512 + threadIdx.x * 2;
    float rg0 = 0.f, rg1 = 0.f, rv0 = 0.f, rv1 = 0.f;
    for (int p = 0; p < c; p++) {
        size_t o = ((size_t)(b * NCHUNK + p)) * D_MODEL + d;
        float2 a  = *(const float2*)(sg + o);
        float2 bb = *(const float2*)(sgv + o);
        rg0 += a.x;  rg1 += a.y;
        rv0 += bb.x; rv1 += bb.y;
    }
    for (int i = 0; i < LCHUNK; i++) {
        int s = c * LCHUNK + i;
        size_t idx = ((size_t)(b * SEQ + s)) * D_MODEL + d;
        float2 gf = bf16pair_to_f2(*(const unsigned int*)(g + idx));
        float2 vf = bf16pair_to_f2(*(const unsigned int*)(v + idx));
        rv0 += gf.x * vf.x; rg0 += gf.x;
        rv1 += gf.y * vf.y; rg1 += gf.y;
        float2 xv = *(const float2*)(x + idx);
        float2 ov;
        ov.x = xv.x + rv0 / (rg0 + 1e-6f);
        ov.y = xv.y + rv1 / (rg1 + 1e-6f);
        *(float2*)(out + idx) = ov;
    }
}

// ---------------------------------------------------------------- launcher
extern "C" void kernel_launch(void* const* d_in, const int* in_sizes, int n_in,
                              void* d_out, int out_size, void* d_ws, size_t ws_size,
                              hipStream_t stream) {
    (void)in_sizes; (void)n_in; (void)out_size; (void)ws_size;
    const float* x       = (const float*)d_in[0];
    const float* ln1_g   = (const float*)d_in[1];
    const float* ln1_b   = (const float*)d_in[2];
    const float* ln2_g   = (const float*)d_in[3];
    const float* ln2_b   = (const float*)d_in[4];
    const float* gate_w  = (const float*)d_in[5];
    const float* gate_b  = (const float*)d_in[6];
    const float* value_w = (const float*)d_in[7];
    const float* value_b = (const float*)d_in[8];
    const float* ffn_w1  = (const float*)d_in[9];
    const float* ffn_b1  = (const float*)d_in[10];
    const float* ffn_w2  = (const float*)d_in[11];
    const float* ffn_b2  = (const float*)d_in[12];
    float* out = (float*)d_out;

    char* ws = (char*)d_ws;
    const size_t MB = 1024 * 1024;
    bf16_t* wgv_t = (bf16_t*)(ws + 0 * MB);     // (2048,1024) bf16   4 MB
    bf16_t* w1_t  = (bf16_t*)(ws + 4 * MB);     // (4096,1024) bf16   8 MB
    bf16_t* w2_t  = (bf16_t*)(ws + 12 * MB);    // (1024,4096) bf16   8 MB
    bf16_t* h     = (bf16_t*)(ws + 20 * MB);    // (16384,1024) bf16 32 MB (reused as h2)
    bf16_t* g     = (bf16_t*)(ws + 52 * MB);    // (16384,1024) bf16 32 MB
    bf16_t* v     = (bf16_t*)(ws + 84 * MB);    // (16384,1024) bf16 32 MB
    float*  sg    = (float*)(ws + 116 * MB);    // (4,64,1024) f32    1 MB
    float*  sgv   = (float*)(ws + 117 * MB);    // (4,64,1024) f32    1 MB
    bf16_t* act   = (bf16_t*)(ws + 118 * MB);   // (16384,4096) bf16 128 MB

    // 1. all weight transposes in one launch
    transpose_all<<<10240, 256, 0, stream>>>(gate_w, value_w, ffn_w1, ffn_w2,
                                             wgv_t, w1_t, w2_t);

    // 2. h = LN1(x)
    ln_kernel<<<M_ROWS, 256, 0, stream>>>(x, ln1_g, ln1_b, h);

    // 3. fused: g = sigmoid(h@gate_w + gate_b); v = h@value_w + value_b
    //    TN=8, TPB=2, KT=16 -> 256 persistent blocks
    gemm256<4, 8, 2, 4><<<256, 512, 0, stream>>>(
        h, wgv_t, gate_b, value_b, nullptr, g, v, M_ROWS, 2048, 1024);

    // 4. x_new = x + cumsum(g*v)/(cumsum(g)+eps)  -> d_out
    scan_partial<<<BATCH * NCHUNK * 2, 256, 0, stream>>>(g, v, sg, sgv);
    scan_apply<<<BATCH * NCHUNK * 2, 256, 0, stream>>>(g, v, x, sg, sgv, out);

    // 5. h2 = LN2(x_new)
    ln_kernel<<<M_ROWS, 256, 0, stream>>>(out, ln2_g, ln2_b, h);

    // 6. act = gelu(h2@ffn_w1 + ffn_b1)   TN=16, TPB=4, KT=16
    gemm256<2, 16, 4, 4><<<256, 512, 0, stream>>>(
        h, w1_t, ffn_b1, nullptr, nullptr, act, nullptr, M_ROWS, 4096, 1024);

    // 7. out = x_new + act@ffn_w2 + ffn_b2   TN=4, TPB=1, KT=64
    gemm256<3, 4, 1, 6><<<256, 512, 0, stream>>>(
        act, w2_t, ffn_b2, nullptr, out, out, nullptr, M_ROWS, 1024, 4096);
}

// Round 5
// 596.318 us; speedup vs baseline: 1.1837x; 1.1837x over previous
//
#include <hip/hip_runtime.h>
#include <cstdint>
#include <cstddef>

#define D_MODEL 1024
#define SEQ     4096
#define BATCH   4
#define M_ROWS  (BATCH*SEQ)   // 16384
#define NCHUNK  64
#define LCHUNK  (SEQ/NCHUNK)  // 64

typedef __bf16 bf16_t;
typedef __bf16 bf16x8 __attribute__((ext_vector_type(8)));
typedef __bf16 bf16x4 __attribute__((ext_vector_type(4)));
typedef float  f32x4  __attribute__((ext_vector_type(4)));

// ---------------------------------------------------------------- utilities
__device__ __forceinline__ void load_lds_128(const bf16_t* g, bf16_t* l) {
    __builtin_amdgcn_global_load_lds(
        (const __attribute__((address_space(1))) unsigned int*)g,
        (__attribute__((address_space(3))) unsigned int*)l,
        16, 0, 0);
}

__device__ __forceinline__ float2 bf16pair_to_f2(unsigned int u) {
    union { unsigned int i; float f; } a, b;
    a.i = u << 16;          // low element
    b.i = u & 0xffff0000u;  // high element
    float2 r; r.x = a.f; r.y = b.f; return r;
}

// tanh-form GELU: max |err| vs exact erf-GELU ~5e-4, below bf16 quantization
// of the activation tensor; one v_exp instead of erff's ~20-op polynomial.
__device__ __forceinline__ float gelu_f(float x) {
    float t = x * x;
    float u = x * (1.5957691216f + 0.07135481627f * t);   // 2c(x+0.044715x^3)
    return x / (1.0f + __expf(-u));
}

// ---------------------------------------------- fused weight convert+transpose
// all four weights in one launch; in: f32 (R,C) row-major -> out: bf16 (C,R)
__global__ __launch_bounds__(256)
void transpose_all(const float* __restrict__ gate_w, const float* __restrict__ value_w,
                   const float* __restrict__ ffn_w1, const float* __restrict__ ffn_w2,
                   bf16_t* __restrict__ wgv_t, bf16_t* __restrict__ w1_t,
                   bf16_t* __restrict__ w2_t) {
    int id = blockIdx.x;
    const float* in; bf16_t* outp; int R, C, bx, by;
    if (id < 1024)      { in = gate_w;  outp = wgv_t;               R = 1024; C = 1024; bx = id & 31;  by = id >> 5; }
    else if (id < 2048) { id -= 1024; in = value_w; outp = wgv_t + 1024*1024; R = 1024; C = 1024; bx = id & 31;  by = id >> 5; }
    else if (id < 6144) { id -= 2048; in = ffn_w1;  outp = w1_t;    R = 1024; C = 4096; bx = id & 127; by = id >> 7; }
    else                { id -= 6144; in = ffn_w2;  outp = w2_t;    R = 4096; C = 1024; bx = id & 31;  by = id >> 5; }
    __shared__ float t[32][33];
    int tx = threadIdx.x & 31, ty = threadIdx.x >> 5;   // 32 x 8
    int c0 = bx * 32, r0 = by * 32;
    #pragma unroll
    for (int j = 0; j < 32; j += 8)
        t[ty + j][tx] = in[(size_t)(r0 + ty + j) * C + c0 + tx];
    __syncthreads();
    #pragma unroll
    for (int j = 0; j < 32; j += 8)
        outp[(size_t)(c0 + ty + j) * R + r0 + tx] = (bf16_t)t[tx][ty + j];
}

// ---------------------------------------------------------------- layernorm
__global__ __launch_bounds__(256)
void ln_kernel(const float* __restrict__ x, const float* __restrict__ gamma,
               const float* __restrict__ beta, bf16_t* __restrict__ h) {
    int row = blockIdx.x;
    int tid = threadIdx.x;
    const float4* xr = (const float4*)(x + (size_t)row * D_MODEL);
    float4 v = xr[tid];
    float s  = v.x + v.y + v.z + v.w;
    float ss = v.x*v.x + v.y*v.y + v.z*v.z + v.w*v.w;
    #pragma unroll
    for (int off = 32; off; off >>= 1) {
        s  += __shfl_down(s, off);
        ss += __shfl_down(ss, off);
    }
    __shared__ float red[8];
    int wave = tid >> 6, lane = tid & 63;
    if (lane == 0) { red[wave] = s; red[4 + wave] = ss; }
    __syncthreads();
    if (tid == 0) {
        float S  = red[0] + red[1] + red[2] + red[3];
        float SS = red[4] + red[5] + red[6] + red[7];
        float mean = S * (1.0f / D_MODEL);
        float var  = SS * (1.0f / D_MODEL) - mean * mean;
        red[0] = mean;
        red[1] = rsqrtf(var + 1e-5f);
    }
    __syncthreads();
    float mean = red[0], rstd = red[1];
    float4 gv = ((const float4*)gamma)[tid];
    float4 bv = ((const float4*)beta)[tid];
    bf16x4 o;
    o[0] = (bf16_t)((v.x - mean) * rstd * gv.x + bv.x);
    o[1] = (bf16_t)((v.y - mean) * rstd * gv.y + bv.y);
    o[2] = (bf16_t)((v.z - mean) * rstd * gv.z + bv.z);
    o[3] = (bf16_t)((v.w - mean) * rstd * gv.w + bv.w);
    ((bf16x4*)h)[(size_t)row * (D_MODEL / 4) + tid] = o;
}

// ------------------------------------------ GEMM 256x256, 8-phase, persistent
// (r2 GEMM, reverted verbatim: best measured at 166 us / 36% MfmaUtil.)
// r4's A-ring-of-3 regressed to 27.8% -- rotating LDS pointers defeat the
// compiler's alias analysis of in-flight LDS-DMA (static buffer names only).
// This schedule was re-derived in r4's analysis as the LEGAL-MAXIMUM-slack
// 2-buffer half-tile schedule: stage map P1,2:A(t+1); P3,4:B(t+2); P5,6:A(t+2);
// P7,8:B(t+3) with vmcnt(4) at P4/P8 (vmcnt(6) would leave A(t+1).h1 undrained
// at its P5 read -- illegal). 36% is this structure's plateau on this chip.
#define PHASE_MID() do { __builtin_amdgcn_s_barrier(); \
    asm volatile("s_waitcnt lgkmcnt(0)" ::: "memory"); \
    __builtin_amdgcn_s_setprio(1); } while (0)
#define PHASE_END() do { __builtin_amdgcn_s_setprio(0); \
    __builtin_amdgcn_s_barrier(); } while (0)
#define PHASE_END_VM() do { __builtin_amdgcn_s_setprio(0); \
    asm volatile("s_waitcnt vmcnt(4)" ::: "memory"); \
    __builtin_amdgcn_s_barrier(); } while (0)

#define LDA4(BUF, MB) do { _Pragma("unroll") for (int m_ = 0; m_ < 4; ++m_) { \
    af[m_][0] = *(const bf16x8*)((BUF) + aoff0 + ((MB)*4 + m_) * 1024); \
    af[m_][1] = *(const bf16x8*)((BUF) + aoff1 + ((MB)*4 + m_) * 1024); } } while (0)
#define LDB2(BUF, NLO) do { _Pragma("unroll") for (int n_ = 0; n_ < 2; ++n_) { \
    bfr[(NLO)+n_][0] = *(const bf16x8*)((BUF) + boff0 + ((NLO)+n_) * 1024); \
    bfr[(NLO)+n_][1] = *(const bf16x8*)((BUF) + boff1 + ((NLO)+n_) * 1024); } } while (0)
#define MFMA_HALF(MB, NLO) do { _Pragma("unroll") for (int m_ = 0; m_ < 4; ++m_) { \
    _Pragma("unroll") for (int n_ = 0; n_ < 2; ++n_) { \
        acc[(MB)*4 + m_][(NLO) + n_] = __builtin_amdgcn_mfma_f32_16x16x32_bf16( \
            bfr[(NLO)+n_][0], af[m_][0], acc[(MB)*4 + m_][(NLO) + n_], 0, 0, 0); \
        acc[(MB)*4 + m_][(NLO) + n_] = __builtin_amdgcn_mfma_f32_16x16x32_bf16( \
            bfr[(NLO)+n_][1], af[m_][1], acc[(MB)*4 + m_][(NLO) + n_], 0, 0, 0); } } } while (0)

template <int MODE, int TN, int TPB, int LKT>
__global__ __launch_bounds__(512, 2)
void gemm256(const bf16_t* __restrict__ A, const bf16_t* __restrict__ Bt,
             const float* __restrict__ bias, const float* __restrict__ bias2,
             const float* __restrict__ xres,
             void* __restrict__ out, void* __restrict__ out2,
             int M, int N, int K) {
    __shared__ __align__(16) bf16_t lds[2][2][256 * 64];   // [buf][A=0/B=1], 128 KiB

    const int KT = 1 << LKT;       // K-tiles per output tile (K/64)
    const int S  = TPB * KT;       // stream length
    const int NI = S >> 1;         // iterations (2 K-tiles each)

    const int tid  = threadIdx.x;
    const int lane = tid & 63;
    const int wave = tid >> 6;
    const int wm   = wave >> 2;      // 0..1  (m half)
    const int wn   = wave & 3;       // 0..3  (n quarter)

    const int L    = blockIdx.x;
    const int i    = L >> 3;
    const int ngrp = i & 3;                       // TN/TPB == 4 for all shapes
    const int mb   = (L & 7) + 8 * (i >> 2);      // XCD-local m-band
    const int m0   = mb * 256;
    const int n00  = ngrp * TPB * 256;            // first owned n-tile

    f32x4 acc[8][4];
    #pragma unroll
    for (int ii = 0; ii < 8; ii++)
        #pragma unroll
        for (int j = 0; j < 4; j++) acc[ii][j] = (f32x4){0.f, 0.f, 0.f, 0.f};

    // staging invariants: row = tid>>3 (0..63 per half-load), source col8
    // pre-swizzled by row&7 so linear LDS holds the XOR layout.
    const int rr = tid >> 3;                        // 0..63
    const int sc = ((tid & 7) ^ (rr & 7)) * 8;      // swizzled col (bf16 units)
    const bf16_t* pa0 = A  + ((size_t)(m0  + rr)) * K + sc;
    const bf16_t* pb0 = Bt + ((size_t)(n00 + rr)) * K + sc;
    const size_t rstep   = (size_t)64 * K;          // rows 64..127 of a half
    const size_t hstep   = rstep * 2;               // half-tile stride (128 rows)
    const size_t nstride = (size_t)256 * K;         // next n-tile of B

    // stream-tile address helpers (A is periodic in KT: same m-band every tile)
    #define PA(s) (pa0 + (((s) & (KT - 1)) << 6))
    #define PB(s) (pb0 + (size_t)((s) >> LKT) * nstride + (((s) & (KT - 1)) << 6))

    // frag-read invariants
    const int l16 = lane & 15, quad = lane >> 4, swz = l16 & 7;
    const int aoff0 = (wm*128 + l16)*64 + ((quad    ) ^ swz)*8;
    const int aoff1 = (wm*128 + l16)*64 + ((quad + 4) ^ swz)*8;
    const int boff0 = (wn*64  + l16)*64 + ((quad    ) ^ swz)*8;
    const int boff1 = (wn*64  + l16)*64 + ((quad + 4) ^ swz)*8;

    bf16_t* LA0 = &lds[0][0][0]; bf16_t* LB0 = &lds[0][1][0];
    bf16_t* LA1 = &lds[1][0][0]; bf16_t* LB1 = &lds[1][1][0];

    auto STAGE = [&](const bf16_t* gsrc, bf16_t* dst) {
        load_lds_128(gsrc,         dst + tid * 8);
        load_lds_128(gsrc + rstep, dst + 4096 + tid * 8);
    };

    // prologue: B(0), A(0), B(1)  (6 half-tiles = 12 loads)
    STAGE(PB(0),         LB0);
    STAGE(PB(0) + hstep, LB0 + 8192);
    STAGE(PA(0),         LA0);
    STAGE(PA(0) + hstep, LA0 + 8192);
    STAGE(PB(1),         LB1);
    STAGE(PB(1) + hstep, LB1 + 8192);
    asm volatile("s_waitcnt vmcnt(4)" ::: "memory");   // tile 0 landed
    __builtin_amdgcn_s_barrier();

    #pragma unroll 1
    for (int it = 0; it < NI; ++it) {
        const int s1 = 2*it + 1;
        const int s2 = (2*it + 2 < S) ? 2*it + 2 : S - 1;   // clamp = tail junk
        const int s3 = (2*it + 3 < S) ? 2*it + 3 : S - 1;
        const bf16_t* a1 = PA(s1);
        const bf16_t* a2 = PA(s2);
        const bf16_t* b2 = PB(s2);
        const bf16_t* b3 = PB(s3);

        bf16x8 af[4][2], bfr[4][2];

        // P1
        LDA4(LA0, 0); LDB2(LB0, 0);
        STAGE(a1, LA1);
        PHASE_MID(); MFMA_HALF(0, 0); PHASE_END();
        // P2
        LDB2(LB0, 2);
        STAGE(a1 + hstep, LA1 + 8192);
        PHASE_MID(); MFMA_HALF(0, 2); PHASE_END();
        // P3
        LDA4(LA0, 1);
        STAGE(b2, LB0);
        PHASE_MID(); MFMA_HALF(1, 0); PHASE_END();
        // P4
        STAGE(b2 + hstep, LB0 + 8192);
        PHASE_MID(); MFMA_HALF(1, 2); PHASE_END_VM();   // tile s1 landed
        // P5
        LDA4(LA1, 0); LDB2(LB1, 0);
        STAGE(a2, LA0);
        PHASE_MID(); MFMA_HALF(0, 0); PHASE_END();
        // P6
        LDB2(LB1, 2);
        STAGE(a2 + hstep, LA0 + 8192);
        PHASE_MID(); MFMA_HALF(0, 2); PHASE_END();
        // P7
        LDA4(LA1, 1);
        STAGE(b3, LB1);
        PHASE_MID(); MFMA_HALF(1, 0); PHASE_END();
        // P8
        STAGE(b3 + hstep, LB1 + 8192);
        PHASE_MID(); MFMA_HALF(1, 2); PHASE_END_VM();   // tile s2 landed

        // ---- output-tile boundary: epilogue overlaps next tile's in-flight
        // loads (staged at P5-P8 above). Stores inflate vmcnt; the next
        // vmcnt(4) simply over-waits on them (correct, stores are older
        // than the protected loads).
        if (((it + 1) & ((KT >> 1) - 1)) == 0) {
            const int tdone = (2*it + 1) >> LKT;
            const int nn0 = n00 + tdone * 256;
            #pragma unroll
            for (int mt = 0; mt < 8; ++mt) {
                int row = m0 + wm * 128 + mt * 16 + l16;
                #pragma unroll
                for (int nt = 0; nt < 4; ++nt) {
                    int col = nn0 + wn * 64 + nt * 16 + quad * 4;
                    f32x4 a = acc[mt][nt];
                    if (MODE == 4) {
                        bool isV = (nn0 >= 1024);         // tile-uniform
                        int c1 = col & 1023;
                        float4 bv = *(const float4*)((isV ? bias2 : bias) + c1);
                        float4 val;
                        val.x = a[0] + bv.x; val.y = a[1] + bv.y;
                        val.z = a[2] + bv.z; val.w = a[3] + bv.w;
                        if (!isV) {
                            val.x = 1.0f / (1.0f + __expf(-val.x));
                            val.y = 1.0f / (1.0f + __expf(-val.y));
                            val.z = 1.0f / (1.0f + __expf(-val.z));
                            val.w = 1.0f / (1.0f + __expf(-val.w));
                        }
                        bf16x4 p;
                        p[0] = (bf16_t)val.x; p[1] = (bf16_t)val.y;
                        p[2] = (bf16_t)val.z; p[3] = (bf16_t)val.w;
                        bf16_t* o = (bf16_t*)(isV ? out2 : out);
                        *(bf16x4*)(o + (size_t)row * 1024 + c1) = p;
                    } else if (MODE == 2) {
                        float4 bv = *(const float4*)(bias + col);
                        bf16x4 p;
                        p[0] = (bf16_t)gelu_f(a[0] + bv.x);
                        p[1] = (bf16_t)gelu_f(a[1] + bv.y);
                        p[2] = (bf16_t)gelu_f(a[2] + bv.z);
                        p[3] = (bf16_t)gelu_f(a[3] + bv.w);
                        *(bf16x4*)((bf16_t*)out + (size_t)row * N + col) = p;
                    } else { // MODE 3
                        float4 bv = *(const float4*)(bias + col);
                        float4 xr = *(const float4*)(xres + (size_t)row * N + col);
                        float4 val;
                        val.x = xr.x + a[0] + bv.x; val.y = xr.y + a[1] + bv.y;
                        val.z = xr.z + a[2] + bv.z; val.w = xr.w + a[3] + bv.w;
                        *(float4*)((float*)out + (size_t)row * N + col) = val;
                    }
                    acc[mt][nt] = (f32x4){0.f, 0.f, 0.f, 0.f};
                }
            }
        }
    }

    // drain tail junk LDS-DMA before the workgroup can retire
    asm volatile("s_waitcnt vmcnt(0)" ::: "memory");
    #undef PA
    #undef PB
}

// ---------------------------------------------------------------- scan
// r5: widened loads per Guideline 13 -- g/v as uint2 (4 bf16 = 8 B/lane),
// x/out/partials as float4 (16 B/lane). 128-thread blocks, 4 d-cols/thread,
// same grid (512 blocks): 1024 waves total, identical traffic, half the
// load instructions.
// phase A: per-chunk sums of g and g*v
__global__ __launch_bounds__(128)
void scan_partial(const bf16_t* __restrict__ g, const bf16_t* __restrict__ v,
                  float* __restrict__ sg, float* __restrict__ sgv) {
    int dt = blockIdx.x & 1;
    int c  = (blockIdx.x >> 1) & (NCHUNK - 1);
    int b  = blockIdx.x >> 7;
    int d  = dt * 512 + threadIdx.x * 4;
    float s0 = 0.f, s1 = 0.f, s2 = 0.f, s3 = 0.f;
    float t0 = 0.f, t1 = 0.f, t2 = 0.f, t3 = 0.f;
    #pragma unroll 4
    for (int i = 0; i < LCHUNK; i++) {
        size_t idx = ((size_t)(b * SEQ + c * LCHUNK + i)) * D_MODEL + d;
        uint2 gu = *(const uint2*)(g + idx);
        uint2 vu = *(const uint2*)(v + idx);
        float2 ga = bf16pair_to_f2(gu.x), gb = bf16pair_to_f2(gu.y);
        float2 va = bf16pair_to_f2(vu.x), vb = bf16pair_to_f2(vu.y);
        s0 += ga.x; s1 += ga.y; s2 += gb.x; s3 += gb.y;
        t0 += ga.x * va.x; t1 += ga.y * va.y;
        t2 += gb.x * vb.x; t3 += gb.y * vb.y;
    }
    size_t o = ((size_t)(b * NCHUNK + c)) * D_MODEL + d;
    *(float4*)(sg + o)  = make_float4(s0, s1, s2, s3);
    *(float4*)(sgv + o) = make_float4(t0, t1, t2, t3);
}

// phase B+C fused: each block sums partials of chunks < c (L2-resident),
// then applies x_new = x + cumsum(g*v)/(cumsum(g)+eps)
__global__ __launch_bounds__(128)
void scan_apply(const bf16_t* __restrict__ g, const bf16_t* __restrict__ v,
                const float* __restrict__ x, const float* __restrict__ sg,
                const float* __restrict__ sgv, float* __restrict__ out) {
    int dt = blockIdx.x & 1;
    int c  = (blockIdx.x >> 1) & (NCHUNK - 1);
    int b  = blockIdx.x >> 7;
    int d  = dt * 512 + threadIdx.x * 4;
    float rg0 = 0.f, rg1 = 0.f, rg2 = 0.f, rg3 = 0.f;
    float rv0 = 0.f, rv1 = 0.f, rv2 = 0.f, rv3 = 0.f;
    for (int p = 0; p < c; p++) {
        size_t o = ((size_t)(b * NCHUNK + p)) * D_MODEL + d;
        float4 a  = *(const float4*)(sg + o);
        float4 bb = *(const float4*)(sgv + o);
        rg0 += a.x;  rg1 += a.y;  rg2 += a.z;  rg3 += a.w;
        rv0 += bb.x; rv1 += bb.y; rv2 += bb.z; rv3 += bb.w;
    }
    #pragma unroll 2
    for (int i = 0; i < LCHUNK; i++) {
        size_t idx = ((size_t)(b * SEQ + c * LCHUNK + i)) * D_MODEL + d;
        uint2 gu = *(const uint2*)(g + idx);
        uint2 vu = *(const uint2*)(v + idx);
        float2 ga = bf16pair_to_f2(gu.x), gb = bf16pair_to_f2(gu.y);
        float2 va = bf16pair_to_f2(vu.x), vb = bf16pair_to_f2(vu.y);
        rg0 += ga.x; rv0 += ga.x * va.x;
        rg1 += ga.y; rv1 += ga.y * va.y;
        rg2 += gb.x; rv2 += gb.x * vb.x;
        rg3 += gb.y; rv3 += gb.y * vb.y;
        float4 xv = *(const float4*)(x + idx);
        float4 ov;
        ov.x = xv.x + rv0 / (rg0 + 1e-6f);
        ov.y = xv.y + rv1 / (rg1 + 1e-6f);
        ov.z = xv.z + rv2 / (rg2 + 1e-6f);
        ov.w = xv.w + rv3 / (rg3 + 1e-6f);
        *(float4*)(out + idx) = ov;
    }
}

// ---------------------------------------------------------------- launcher
extern "C" void kernel_launch(void* const* d_in, const int* in_sizes, int n_in,
                              void* d_out, int out_size, void* d_ws, size_t ws_size,
                              hipStream_t stream) {
    (void)in_sizes; (void)n_in; (void)out_size; (void)ws_size;
    const float* x       = (const float*)d_in[0];
    const float* ln1_g   = (const float*)d_in[1];
    const float* ln1_b   = (const float*)d_in[2];
    const float* ln2_g   = (const float*)d_in[3];
    const float* ln2_b   = (const float*)d_in[4];
    const float* gate_w  = (const float*)d_in[5];
    const float* gate_b  = (const float*)d_in[6];
    const float* value_w = (const float*)d_in[7];
    const float* value_b = (const float*)d_in[8];
    const float* ffn_w1  = (const float*)d_in[9];
    const float* ffn_b1  = (const float*)d_in[10];
    const float* ffn_w2  = (const float*)d_in[11];
    const float* ffn_b2  = (const float*)d_in[12];
    float* out = (float*)d_out;

    char* ws = (char*)d_ws;
    const size_t MB = 1024 * 1024;
    bf16_t* wgv_t = (bf16_t*)(ws + 0 * MB);     // (2048,1024) bf16   4 MB
    bf16_t* w1_t  = (bf16_t*)(ws + 4 * MB);     // (4096,1024) bf16   8 MB
    bf16_t* w2_t  = (bf16_t*)(ws + 12 * MB);    // (1024,4096) bf16   8 MB
    bf16_t* h     = (bf16_t*)(ws + 20 * MB);    // (16384,1024) bf16 32 MB (reused as h2)
    bf16_t* g     = (bf16_t*)(ws + 52 * MB);    // (16384,1024) bf16 32 MB
    bf16_t* v     = (bf16_t*)(ws + 84 * MB);    // (16384,1024) bf16 32 MB
    float*  sg    = (float*)(ws + 116 * MB);    // (4,64,1024) f32    1 MB
    float*  sgv   = (float*)(ws + 117 * MB);    // (4,64,1024) f32    1 MB
    bf16_t* act   = (bf16_t*)(ws + 118 * MB);   // (16384,4096) bf16 128 MB

    // 1. all weight transposes in one launch
    transpose_all<<<10240, 256, 0, stream>>>(gate_w, value_w, ffn_w1, ffn_w2,
                                             wgv_t, w1_t, w2_t);

    // 2. h = LN1(x)
    ln_kernel<<<M_ROWS, 256, 0, stream>>>(x, ln1_g, ln1_b, h);

    // 3. fused: g = sigmoid(h@gate_w + gate_b); v = h@value_w + value_b
    //    TN=8, TPB=2, KT=16 -> 256 persistent blocks
    gemm256<4, 8, 2, 4><<<256, 512, 0, stream>>>(
        h, wgv_t, gate_b, value_b, nullptr, g, v, M_ROWS, 2048, 1024);

    // 4. x_new = x + cumsum(g*v)/(cumsum(g)+eps)  -> d_out
    scan_partial<<<BATCH * NCHUNK * 2, 128, 0, stream>>>(g, v, sg, sgv);
    scan_apply<<<BATCH * NCHUNK * 2, 128, 0, stream>>>(g, v, x, sg, sgv, out);

    // 5. h2 = LN2(x_new)
    ln_kernel<<<M_ROWS, 256, 0, stream>>>(out, ln2_g, ln2_b, h);

    // 6. act = gelu(h2@ffn_w1 + ffn_b1)   TN=16, TPB=4, KT=16
    gemm256<2, 16, 4, 4><<<256, 512, 0, stream>>>(
        h, w1_t, ffn_b1, nullptr, nullptr, act, nullptr, M_ROWS, 4096, 1024);

    // 7. out = x_new + act@ffn_w2 + ffn_b2   TN=4, TPB=1, KT=64
    gemm256<3, 4, 1, 6><<<256, 512, 0, stream>>>(
        act, w2_t, ffn_b2, nullptr, out, out, nullptr, M_ROWS, 1024, 4096);
}

// Round 6
// 570.207 us; speedup vs baseline: 1.2379x; 1.0458x over previous
//
#include <hip/hip_runtime.h>
#include <cstdint>
#include <cstddef>

#define D_MODEL 1024
#define SEQ     4096
#define BATCH   4
#define M_ROWS  (BATCH*SEQ)   // 16384
#define NCHUNK  64
#define LCHUNK  (SEQ/NCHUNK)  // 64

typedef __bf16 bf16_t;
typedef __bf16 bf16x8 __attribute__((ext_vector_type(8)));
typedef __bf16 bf16x4 __attribute__((ext_vector_type(4)));
typedef float  f32x4  __attribute__((ext_vector_type(4)));

// ---------------------------------------------------------------- utilities
__device__ __forceinline__ void load_lds_128(const bf16_t* g, bf16_t* l) {
    __builtin_amdgcn_global_load_lds(
        (const __attribute__((address_space(1))) unsigned int*)g,
        (__attribute__((address_space(3))) unsigned int*)l,
        16, 0, 0);
}

__device__ __forceinline__ float2 bf16pair_to_f2(unsigned int u) {
    union { unsigned int i; float f; } a, b;
    a.i = u << 16;          // low element
    b.i = u & 0xffff0000u;  // high element
    float2 r; r.x = a.f; r.y = b.f; return r;
}

// tanh-form GELU: max |err| vs exact erf-GELU ~5e-4, below bf16 quantization
// of the activation tensor; one v_exp instead of erff's ~20-op polynomial.
__device__ __forceinline__ float gelu_f(float x) {
    float t = x * x;
    float u = x * (1.5957691216f + 0.07135481627f * t);   // 2c(x+0.044715x^3)
    return x / (1.0f + __expf(-u));
}

// ---------------------------------------------- fused weight convert+transpose
// all four weights in one launch; in: f32 (R,C) row-major -> out: bf16 (C,R)
__global__ __launch_bounds__(256)
void transpose_all(const float* __restrict__ gate_w, const float* __restrict__ value_w,
                   const float* __restrict__ ffn_w1, const float* __restrict__ ffn_w2,
                   bf16_t* __restrict__ wgv_t, bf16_t* __restrict__ w1_t,
                   bf16_t* __restrict__ w2_t) {
    int id = blockIdx.x;
    const float* in; bf16_t* outp; int R, C, bx, by;
    if (id < 1024)      { in = gate_w;  outp = wgv_t;               R = 1024; C = 1024; bx = id & 31;  by = id >> 5; }
    else if (id < 2048) { id -= 1024; in = value_w; outp = wgv_t + 1024*1024; R = 1024; C = 1024; bx = id & 31;  by = id >> 5; }
    else if (id < 6144) { id -= 2048; in = ffn_w1;  outp = w1_t;    R = 1024; C = 4096; bx = id & 127; by = id >> 7; }
    else                { id -= 6144; in = ffn_w2;  outp = w2_t;    R = 4096; C = 1024; bx = id & 31;  by = id >> 5; }
    __shared__ float t[32][33];
    int tx = threadIdx.x & 31, ty = threadIdx.x >> 5;   // 32 x 8
    int c0 = bx * 32, r0 = by * 32;
    #pragma unroll
    for (int j = 0; j < 32; j += 8)
        t[ty + j][tx] = in[(size_t)(r0 + ty + j) * C + c0 + tx];
    __syncthreads();
    #pragma unroll
    for (int j = 0; j < 32; j += 8)
        outp[(size_t)(c0 + ty + j) * R + r0 + tx] = (bf16_t)t[tx][ty + j];
}

// ---------------------------------------------------------------- layernorm
__global__ __launch_bounds__(256)
void ln_kernel(const float* __restrict__ x, const float* __restrict__ gamma,
               const float* __restrict__ beta, bf16_t* __restrict__ h) {
    int row = blockIdx.x;
    int tid = threadIdx.x;
    const float4* xr = (const float4*)(x + (size_t)row * D_MODEL);
    float4 v = xr[tid];
    float s  = v.x + v.y + v.z + v.w;
    float ss = v.x*v.x + v.y*v.y + v.z*v.z + v.w*v.w;
    #pragma unroll
    for (int off = 32; off; off >>= 1) {
        s  += __shfl_down(s, off);
        ss += __shfl_down(ss, off);
    }
    __shared__ float red[8];
    int wave = tid >> 6, lane = tid & 63;
    if (lane == 0) { red[wave] = s; red[4 + wave] = ss; }
    __syncthreads();
    if (tid == 0) {
        float S  = red[0] + red[1] + red[2] + red[3];
        float SS = red[4] + red[5] + red[6] + red[7];
        float mean = S * (1.0f / D_MODEL);
        float var  = SS * (1.0f / D_MODEL) - mean * mean;
        red[0] = mean;
        red[1] = rsqrtf(var + 1e-5f);
    }
    __syncthreads();
    float mean = red[0], rstd = red[1];
    float4 gv = ((const float4*)gamma)[tid];
    float4 bv = ((const float4*)beta)[tid];
    bf16x4 o;
    o[0] = (bf16_t)((v.x - mean) * rstd * gv.x + bv.x);
    o[1] = (bf16_t)((v.y - mean) * rstd * gv.y + bv.y);
    o[2] = (bf16_t)((v.z - mean) * rstd * gv.z + bv.z);
    o[3] = (bf16_t)((v.w - mean) * rstd * gv.w + bv.w);
    ((bf16x4*)h)[(size_t)row * (D_MODEL / 4) + tid] = o;
}

// -------------- GEMM 256x256, 8 single-barrier phases, persistent stream-K
// A: bf16 (M,K) row-major.  Bt: bf16 (N,K) row-major.
// r6 change: READS-AFTER-BARRIER, ONE barrier per phase.
// Evidence model (fits r0-r5): VALUBusy==MfmaUtil every round -> with 2
// barriers/phase both waves/SIMD are lockstepped: LDS-read window and MFMA
// window serialize (LDS ~2000 + MFMA 1240 ~= measured 3450 cyc/iter). The
// old [reads][barrier][lgkmcnt(0)][MFMA] shape forces a monolithic drain;
// moving reads AFTER the barrier lets the compiler interleave counted lgkm
// waits into the MFMA cluster (m97's verified property) and desyncs waves.
// Phase p = [STAGE][vmcnt if crossing][s_barrier][ds_reads][prio1 MFMA prio0]
//           [lgkmcnt(0) (free: last MFMA consumed all reads)]
// The trailing lgkm0 guarantees phase-p reads complete before any wave
// passes B_{p+1} -> overwrite-after-read audit needs stage >= 2 phases after
// the target's last read:
//   reads:  P1: A.m0-3(LA0)+ALL B(LB0);  P3: A.m4-7(LA0);  P5/P7 same on buf1
//   stages: P1:A(t+1)h0->LA1  P2:A(t+1)h1  P3:B(t+2)h0->LB0  P4:B(t+2)h1
//           P5:A(t+2)h0->LA0  P6:A(t+2)h1  P7:B(t+3)h0->LB1  P8:B(t+3)h1
//   audit: LA1 last read P7prev -> staged P1/P2 (dist 2/3) OK; LB0 last read
//   P1 -> staged P3/P4 OK; LA0 last read P3 -> staged P5/P6 OK; LB1 last
//   read P5 -> staged P7/P8 OK.
// vmcnt(4) BEFORE B_1 and B_5 (after that phase's own stage): at B_1 drains
// through B(t+1)h0, leaves [B(t+1)h1, A(t+1)h0] -> P1-P4's operands A(t),B(t)
// all landed; symmetric at B_5. Verified load-by-load. Persistent stream-K
// grid=256 as r2; tail junk-clamp unchanged (junk regions never re-read,
// stage distances still >=2); vmcnt(0) before epilogue return.
// MODE 2: out_bf16 = gelu_tanh(acc + bias)
// MODE 3: out_f32  = xres + acc + bias
// MODE 4: fused gate/value: n<1024 -> sigmoid(acc+bias) -> out; else acc+bias2 -> out2
#define FENCE() asm volatile("" ::: "memory")
#define BAR() do { FENCE(); __builtin_amdgcn_s_barrier(); FENCE(); } while (0)
#define LGKM0() asm volatile("s_waitcnt lgkmcnt(0)" ::: "memory")
#define VMW4() asm volatile("s_waitcnt vmcnt(4)" ::: "memory")
#define PRIO1() __builtin_amdgcn_s_setprio(1)
#define PRIO0() __builtin_amdgcn_s_setprio(0)

#define LDA4(BUF, MB) do { _Pragma("unroll") for (int m_ = 0; m_ < 4; ++m_) { \
    af[m_][0] = *(const bf16x8*)((BUF) + aoff0 + ((MB)*4 + m_) * 1024); \
    af[m_][1] = *(const bf16x8*)((BUF) + aoff1 + ((MB)*4 + m_) * 1024); } } while (0)
#define LDB4(BUF) do { _Pragma("unroll") for (int n_ = 0; n_ < 4; ++n_) { \
    bfr[n_][0] = *(const bf16x8*)((BUF) + boff0 + n_ * 1024); \
    bfr[n_][1] = *(const bf16x8*)((BUF) + boff1 + n_ * 1024); } } while (0)
#define MFMA_HALF(MB, NLO) do { _Pragma("unroll") for (int m_ = 0; m_ < 4; ++m_) { \
    _Pragma("unroll") for (int n_ = 0; n_ < 2; ++n_) { \
        acc[(MB)*4 + m_][(NLO) + n_] = __builtin_amdgcn_mfma_f32_16x16x32_bf16( \
            bfr[(NLO)+n_][0], af[m_][0], acc[(MB)*4 + m_][(NLO) + n_], 0, 0, 0); \
        acc[(MB)*4 + m_][(NLO) + n_] = __builtin_amdgcn_mfma_f32_16x16x32_bf16( \
            bfr[(NLO)+n_][1], af[m_][1], acc[(MB)*4 + m_][(NLO) + n_], 0, 0, 0); } } } while (0)

template <int MODE, int TN, int TPB, int LKT>
__global__ __launch_bounds__(512, 2)
void gemm256(const bf16_t* __restrict__ A, const bf16_t* __restrict__ Bt,
             const float* __restrict__ bias, const float* __restrict__ bias2,
             const float* __restrict__ xres,
             void* __restrict__ out, void* __restrict__ out2,
             int M, int N, int K) {
    __shared__ __align__(16) bf16_t lds[2][2][256 * 64];   // [buf][A=0/B=1], 128 KiB

    const int KT = 1 << LKT;       // K-tiles per output tile (K/64)
    const int S  = TPB * KT;       // stream length
    const int NI = S >> 1;         // iterations (2 K-tiles each)

    const int tid  = threadIdx.x;
    const int lane = tid & 63;
    const int wave = tid >> 6;
    const int wm   = wave >> 2;      // 0..1  (m half)
    const int wn   = wave & 3;       // 0..3  (n quarter)

    const int L    = blockIdx.x;
    const int i    = L >> 3;
    const int ngrp = i & 3;                       // TN/TPB == 4 for all shapes
    const int mb   = (L & 7) + 8 * (i >> 2);      // XCD-local m-band
    const int m0   = mb * 256;
    const int n00  = ngrp * TPB * 256;            // first owned n-tile

    f32x4 acc[8][4];
    #pragma unroll
    for (int ii = 0; ii < 8; ii++)
        #pragma unroll
        for (int j = 0; j < 4; j++) acc[ii][j] = (f32x4){0.f, 0.f, 0.f, 0.f};

    // staging invariants: row = tid>>3 (0..63 per half-load), source col8
    // pre-swizzled by row&7 so linear LDS holds the XOR layout.
    const int rr = tid >> 3;                        // 0..63
    const int sc = ((tid & 7) ^ (rr & 7)) * 8;      // swizzled col (bf16 units)
    const bf16_t* pa0 = A  + ((size_t)(m0  + rr)) * K + sc;
    const bf16_t* pb0 = Bt + ((size_t)(n00 + rr)) * K + sc;
    const size_t rstep   = (size_t)64 * K;          // rows 64..127 of a half
    const size_t hstep   = rstep * 2;               // half-tile stride (128 rows)
    const size_t nstride = (size_t)256 * K;         // next n-tile of B

    // stream-tile address helpers (A is periodic in KT: same m-band every tile)
    #define PA(s) (pa0 + (((s) & (KT - 1)) << 6))
    #define PB(s) (pb0 + (size_t)((s) >> LKT) * nstride + (((s) & (KT - 1)) << 6))

    // frag-read invariants
    const int l16 = lane & 15, quad = lane >> 4, swz = l16 & 7;
    const int aoff0 = (wm*128 + l16)*64 + ((quad    ) ^ swz)*8;
    const int aoff1 = (wm*128 + l16)*64 + ((quad + 4) ^ swz)*8;
    const int boff0 = (wn*64  + l16)*64 + ((quad    ) ^ swz)*8;
    const int boff1 = (wn*64  + l16)*64 + ((quad + 4) ^ swz)*8;

    bf16_t* LA0 = &lds[0][0][0]; bf16_t* LB0 = &lds[0][1][0];
    bf16_t* LA1 = &lds[1][0][0]; bf16_t* LB1 = &lds[1][1][0];

    auto STAGE = [&](const bf16_t* gsrc, bf16_t* dst) {
        load_lds_128(gsrc,         dst + tid * 8);
        load_lds_128(gsrc + rstep, dst + 4096 + tid * 8);
    };

    // prologue: B(0), A(0), B(1)  (6 half-tiles = 12 loads)
    STAGE(PB(0),         LB0);
    STAGE(PB(0) + hstep, LB0 + 8192);
    STAGE(PA(0),         LA0);
    STAGE(PA(0) + hstep, LA0 + 8192);
    STAGE(PB(1),         LB1);
    STAGE(PB(1) + hstep, LB1 + 8192);
    VMW4();                               // tile 0 landed; B(1) stays in flight
    BAR();

    #pragma unroll 1
    for (int it = 0; it < NI; ++it) {
        const int s1 = 2*it + 1;
        const int s2 = (2*it + 2 < S) ? 2*it + 2 : S - 1;   // clamp = tail junk
        const int s3 = (2*it + 3 < S) ? 2*it + 3 : S - 1;
        const bf16_t* a1 = PA(s1);
        const bf16_t* a2 = PA(s2);
        const bf16_t* b2 = PB(s2);
        const bf16_t* b3 = PB(s3);

        bf16x8 af[4][2], bfr[4][2];

        // P1: stage A(s1)h0 | vmcnt | barrier | read A.m0-3 + all B | mfma
        STAGE(a1, LA1);
        VMW4();
        BAR();
        LDA4(LA0, 0); LDB4(LB0);
        PRIO1(); MFMA_HALF(0, 0); PRIO0(); LGKM0();
        // P2: stage A(s1)h1 | barrier | mfma (pure compute)
        STAGE(a1 + hstep, LA1 + 8192);
        BAR();
        PRIO1(); MFMA_HALF(0, 2); PRIO0();
        // P3: stage B(s2)h0 | barrier | read A.m4-7 | mfma
        STAGE(b2, LB0);
        BAR();
        LDA4(LA0, 1);
        PRIO1(); MFMA_HALF(1, 0); PRIO0(); LGKM0();
        // P4: stage B(s2)h1 | barrier | mfma (pure compute)
        STAGE(b2 + hstep, LB0 + 8192);
        BAR();
        PRIO1(); MFMA_HALF(1, 2); PRIO0();
        // P5: stage A(s2)h0 | vmcnt | barrier | read buf1 A.m0-3 + all B | mfma
        STAGE(a2, LA0);
        VMW4();
        BAR();
        LDA4(LA1, 0); LDB4(LB1);
        PRIO1(); MFMA_HALF(0, 0); PRIO0(); LGKM0();
        // P6: stage A(s2)h1 | barrier | mfma
        STAGE(a2 + hstep, LA0 + 8192);
        BAR();
        PRIO1(); MFMA_HALF(0, 2); PRIO0();
        // P7: stage B(s3)h0 | barrier | read A.m4-7 | mfma
        STAGE(b3, LB1);
        BAR();
        LDA4(LA1, 1);
        PRIO1(); MFMA_HALF(1, 0); PRIO0(); LGKM0();
        // P8: stage B(s3)h1 | barrier | mfma
        STAGE(b3 + hstep, LB1 + 8192);
        BAR();
        PRIO1(); MFMA_HALF(1, 2); PRIO0();

        // ---- output-tile boundary: epilogue overlaps next tile's in-flight
        // loads. Its global loads inflate vmcnt; the next vmcnt(4) over-waits
        // on them (correct: staged loads are older than epilogue loads).
        if (((it + 1) & ((KT >> 1) - 1)) == 0) {
            const int tdone = (2*it + 1) >> LKT;
            const int nn0 = n00 + tdone * 256;
            #pragma unroll
            for (int mt = 0; mt < 8; ++mt) {
                int row = m0 + wm * 128 + mt * 16 + l16;
                #pragma unroll
                for (int nt = 0; nt < 4; ++nt) {
                    int col = nn0 + wn * 64 + nt * 16 + quad * 4;
                    f32x4 a = acc[mt][nt];
                    if (MODE == 4) {
                        bool isV = (nn0 >= 1024);         // tile-uniform
                        int c1 = col & 1023;
                        float4 bv = *(const float4*)((isV ? bias2 : bias) + c1);
                        float4 val;
                        val.x = a[0] + bv.x; val.y = a[1] + bv.y;
                        val.z = a[2] + bv.z; val.w = a[3] + bv.w;
                        if (!isV) {
                            val.x = 1.0f / (1.0f + __expf(-val.x));
                            val.y = 1.0f / (1.0f + __expf(-val.y));
                            val.z = 1.0f / (1.0f + __expf(-val.z));
                            val.w = 1.0f / (1.0f + __expf(-val.w));
                        }
                        bf16x4 p;
                        p[0] = (bf16_t)val.x; p[1] = (bf16_t)val.y;
                        p[2] = (bf16_t)val.z; p[3] = (bf16_t)val.w;
                        bf16_t* o = (bf16_t*)(isV ? out2 : out);
                        *(bf16x4*)(o + (size_t)row * 1024 + c1) = p;
                    } else if (MODE == 2) {
                        float4 bv = *(const float4*)(bias + col);
                        bf16x4 p;
                        p[0] = (bf16_t)gelu_f(a[0] + bv.x);
                        p[1] = (bf16_t)gelu_f(a[1] + bv.y);
                        p[2] = (bf16_t)gelu_f(a[2] + bv.z);
                        p[3] = (bf16_t)gelu_f(a[3] + bv.w);
                        *(bf16x4*)((bf16_t*)out + (size_t)row * N + col) = p;
                    } else { // MODE 3
                        float4 bv = *(const float4*)(bias + col);
                        float4 xr = *(const float4*)(xres + (size_t)row * N + col);
                        float4 val;
                        val.x = xr.x + a[0] + bv.x; val.y = xr.y + a[1] + bv.y;
                        val.z = xr.z + a[2] + bv.z; val.w = xr.w + a[3] + bv.w;
                        *(float4*)((float*)out + (size_t)row * N + col) = val;
                    }
                    acc[mt][nt] = (f32x4){0.f, 0.f, 0.f, 0.f};
                }
            }
        }
    }

    // drain tail junk LDS-DMA before the workgroup can retire
    asm volatile("s_waitcnt vmcnt(0)" ::: "memory");
    #undef PA
    #undef PB
}

// ---------------------------------------------------------------- scan
// widened loads (G13): g/v as uint2 (4 bf16 = 8 B/lane), x/out/partials as
// float4. 128-thread blocks, 4 d-cols/thread, same grid.
// phase A: per-chunk sums of g and g*v
__global__ __launch_bounds__(128)
void scan_partial(const bf16_t* __restrict__ g, const bf16_t* __restrict__ v,
                  float* __restrict__ sg, float* __restrict__ sgv) {
    int dt = blockIdx.x & 1;
    int c  = (blockIdx.x >> 1) & (NCHUNK - 1);
    int b  = blockIdx.x >> 7;
    int d  = dt * 512 + threadIdx.x * 4;
    float s0 = 0.f, s1 = 0.f, s2 = 0.f, s3 = 0.f;
    float t0 = 0.f, t1 = 0.f, t2 = 0.f, t3 = 0.f;
    #pragma unroll 4
    for (int i = 0; i < LCHUNK; i++) {
        size_t idx = ((size_t)(b * SEQ + c * LCHUNK + i)) * D_MODEL + d;
        uint2 gu = *(const uint2*)(g + idx);
        uint2 vu = *(const uint2*)(v + idx);
        float2 ga = bf16pair_to_f2(gu.x), gb = bf16pair_to_f2(gu.y);
        float2 va = bf16pair_to_f2(vu.x), vb = bf16pair_to_f2(vu.y);
        s0 += ga.x; s1 += ga.y; s2 += gb.x; s3 += gb.y;
        t0 += ga.x * va.x; t1 += ga.y * va.y;
        t2 += gb.x * vb.x; t3 += gb.y * vb.y;
    }
    size_t o = ((size_t)(b * NCHUNK + c)) * D_MODEL + d;
    *(float4*)(sg + o)  = make_float4(s0, s1, s2, s3);
    *(float4*)(sgv + o) = make_float4(t0, t1, t2, t3);
}

// phase B+C fused: each block sums partials of chunks < c (L2-resident),
// then applies x_new = x + cumsum(g*v)/(cumsum(g)+eps)
__global__ __launch_bounds__(128)
void scan_apply(const bf16_t* __restrict__ g, const bf16_t* __restrict__ v,
                const float* __restrict__ x, const float* __restrict__ sg,
                const float* __restrict__ sgv, float* __restrict__ out) {
    int dt = blockIdx.x & 1;
    int c  = (blockIdx.x >> 1) & (NCHUNK - 1);
    int b  = blockIdx.x >> 7;
    int d  = dt * 512 + threadIdx.x * 4;
    float rg0 = 0.f, rg1 = 0.f, rg2 = 0.f, rg3 = 0.f;
    float rv0 = 0.f, rv1 = 0.f, rv2 = 0.f, rv3 = 0.f;
    for (int p = 0; p < c; p++) {
        size_t o = ((size_t)(b * NCHUNK + p)) * D_MODEL + d;
        float4 a  = *(const float4*)(sg + o);
        float4 bb = *(const float4*)(sgv + o);
        rg0 += a.x;  rg1 += a.y;  rg2 += a.z;  rg3 += a.w;
        rv0 += bb.x; rv1 += bb.y; rv2 += bb.z; rv3 += bb.w;
    }
    #pragma unroll 2
    for (int i = 0; i < LCHUNK; i++) {
        size_t idx = ((size_t)(b * SEQ + c * LCHUNK + i)) * D_MODEL + d;
        uint2 gu = *(const uint2*)(g + idx);
        uint2 vu = *(const uint2*)(v + idx);
        float2 ga = bf16pair_to_f2(gu.x), gb = bf16pair_to_f2(gu.y);
        float2 va = bf16pair_to_f2(vu.x), vb = bf16pair_to_f2(vu.y);
        rg0 += ga.x; rv0 += ga.x * va.x;
        rg1 += ga.y; rv1 += ga.y * va.y;
        rg2 += gb.x; rv2 += gb.x * vb.x;
        rg3 += gb.y; rv3 += gb.y * vb.y;
        float4 xv = *(const float4*)(x + idx);
        float4 ov;
        ov.x = xv.x + rv0 / (rg0 + 1e-6f);
        ov.y = xv.y + rv1 / (rg1 + 1e-6f);
        ov.z = xv.z + rv2 / (rg2 + 1e-6f);
        ov.w = xv.w + rv3 / (rg3 + 1e-6f);
        *(float4*)(out + idx) = ov;
    }
}

// ---------------------------------------------------------------- launcher
extern "C" void kernel_launch(void* const* d_in, const int* in_sizes, int n_in,
                              void* d_out, int out_size, void* d_ws, size_t ws_size,
                              hipStream_t stream) {
    (void)in_sizes; (void)n_in; (void)out_size; (void)ws_size;
    const float* x       = (const float*)d_in[0];
    const float* ln1_g   = (const float*)d_in[1];
    const float* ln1_b   = (const float*)d_in[2];
    const float* ln2_g   = (const float*)d_in[3];
    const float* ln2_b   = (const float*)d_in[4];
    const float* gate_w  = (const float*)d_in[5];
    const float* gate_b  = (const float*)d_in[6];
    const float* value_w = (const float*)d_in[7];
    const float* value_b = (const float*)d_in[8];
    const float* ffn_w1  = (const float*)d_in[9];
    const float* ffn_b1  = (const float*)d_in[10];
    const float* ffn_w2  = (const float*)d_in[11];
    const float* ffn_b2  = (const float*)d_in[12];
    float* out = (float*)d_out;

    char* ws = (char*)d_ws;
    const size_t MB = 1024 * 1024;
    bf16_t* wgv_t = (bf16_t*)(ws + 0 * MB);     // (2048,1024) bf16   4 MB
    bf16_t* w1_t  = (bf16_t*)(ws + 4 * MB);     // (4096,1024) bf16   8 MB
    bf16_t* w2_t  = (bf16_t*)(ws + 12 * MB);    // (1024,4096) bf16   8 MB
    bf16_t* h     = (bf16_t*)(ws + 20 * MB);    // (16384,1024) bf16 32 MB (reused as h2)
    bf16_t* g     = (bf16_t*)(ws + 52 * MB);    // (16384,1024) bf16 32 MB
    bf16_t* v     = (bf16_t*)(ws + 84 * MB);    // (16384,1024) bf16 32 MB
    float*  sg    = (float*)(ws + 116 * MB);    // (4,64,1024) f32    1 MB
    float*  sgv   = (float*)(ws + 117 * MB);    // (4,64,1024) f32    1 MB
    bf16_t* act   = (bf16_t*)(ws + 118 * MB);   // (16384,4096) bf16 128 MB

    // 1. all weight transposes in one launch
    transpose_all<<<10240, 256, 0, stream>>>(gate_w, value_w, ffn_w1, ffn_w2,
                                             wgv_t, w1_t, w2_t);

    // 2. h = LN1(x)
    ln_kernel<<<M_ROWS, 256, 0, stream>>>(x, ln1_g, ln1_b, h);

    // 3. fused: g = sigmoid(h@gate_w + gate_b); v = h@value_w + value_b
    //    TN=8, TPB=2, KT=16 -> 256 persistent blocks
    gemm256<4, 8, 2, 4><<<256, 512, 0, stream>>>(
        h, wgv_t, gate_b, value_b, nullptr, g, v, M_ROWS, 2048, 1024);

    // 4. x_new = x + cumsum(g*v)/(cumsum(g)+eps)  -> d_out
    scan_partial<<<BATCH * NCHUNK * 2, 128, 0, stream>>>(g, v, sg, sgv);
    scan_apply<<<BATCH * NCHUNK * 2, 128, 0, stream>>>(g, v, x, sg, sgv, out);

    // 5. h2 = LN2(x_new)
    ln_kernel<<<M_ROWS, 256, 0, stream>>>(out, ln2_g, ln2_b, h);

    // 6. act = gelu(h2@ffn_w1 + ffn_b1)   TN=16, TPB=4, KT=16
    gemm256<2, 16, 4, 4><<<256, 512, 0, stream>>>(
        h, w1_t, ffn_b1, nullptr, nullptr, act, nullptr, M_ROWS, 4096, 1024);

    // 7. out = x_new + act@ffn_w2 + ffn_b2   TN=4, TPB=1, KT=64
    gemm256<3, 4, 1, 6><<<256, 512, 0, stream>>>(
        act, w2_t, ffn_b2, nullptr, out, out, nullptr, M_ROWS, 1024, 4096);
}